// Round 1
// 614.760 us; speedup vs baseline: 1.0526x; 1.0526x over previous
//
#include <hip/hip_runtime.h>

typedef unsigned short u16;
typedef __attribute__((ext_vector_type(4))) unsigned short u16x4;
typedef __attribute__((ext_vector_type(8))) short short8;
typedef __attribute__((ext_vector_type(4))) float f32x4;

#define D_MODEL 1024
#define D_FF    4096
#define NB      16
#define NTOK    1024
#define NEXP    8

// round-to-nearest-even fp32 -> bf16
__device__ __forceinline__ u16 f2bf(float f) {
  union { float f; unsigned u; } v; v.f = f;
  unsigned r = v.u + 0x7FFFu + ((v.u >> 16) & 1u);
  return (u16)(r >> 16);
}

// async global->LDS, 16B per lane; LDS dest is wave-uniform base + lane*16
__device__ __forceinline__ void gld16(const void* g, void* l) {
  __builtin_amdgcn_global_load_lds(
      (const __attribute__((address_space(1))) unsigned int*)g,
      (__attribute__((address_space(3))) unsigned int*)l,
      16, 0, 0);
}

// ---------------------------------------------------------------------------
// x fp32 -> bf16 + per-(b,h) column sums (for router mean) via atomics.
__global__ void xcvt_kernel(const float* __restrict__ x, u16* __restrict__ xbf,
                            float* __restrict__ sums) {
  const int b = blockIdx.y;
  const int n0 = blockIdx.x * 16;
  const int t = threadIdx.x;
  const int h0 = t * 4;
  const size_t base = ((size_t)b * NTOK + n0) * D_MODEL + h0;
  const float* xp = x + base;
  u16* op = xbf + base;
  float a0 = 0.f, a1 = 0.f, a2 = 0.f, a3 = 0.f;
#pragma unroll
  for (int r = 0; r < 16; ++r) {
    float4 v = *(const float4*)(xp + (size_t)r * D_MODEL);
    a0 += v.x; a1 += v.y; a2 += v.z; a3 += v.w;
    u16x4 o;
    o.x = f2bf(v.x); o.y = f2bf(v.y); o.z = f2bf(v.z); o.w = f2bf(v.w);
    *(u16x4*)(op + (size_t)r * D_MODEL) = o;
  }
  float* s = sums + b * D_MODEL + h0;
  atomicAdd(s + 0, a0); atomicAdd(s + 1, a1);
  atomicAdd(s + 2, a2); atomicAdd(s + 3, a3);
}

// ---------------------------------------------------------------------------
// Router, parallel over batch: block b computes scores[b][:], argmax.
// used[] is pre-zeroed by the ws memset; plain store of 1 is race-free.
__global__ void router_kernel(const float* __restrict__ sums,
                              const float* __restrict__ Wr,
                              const float* __restrict__ br,
                              int* __restrict__ top1, int* __restrict__ used) {
  __shared__ float part[256][NEXP];
  const int b = blockIdx.x;
  const int t = threadIdx.x;
  float acc[NEXP];
#pragma unroll
  for (int e = 0; e < NEXP; ++e) acc[e] = 0.f;
  const float* s = sums + b * D_MODEL;
  for (int h = t; h < D_MODEL; h += 256) {
    const float sv = s[h];
#pragma unroll
    for (int e = 0; e < NEXP; ++e) acc[e] += sv * Wr[h * NEXP + e];
  }
#pragma unroll
  for (int e = 0; e < NEXP; ++e) part[t][e] = acc[e];
  __syncthreads();
  if (t == 0) {
    float best = -1e30f; int bi = 0;
#pragma unroll
    for (int e = 0; e < NEXP; ++e) {
      float sc = 0.f;
      for (int i = 0; i < 256; ++i) sc += part[i][e];
      sc = sc * (1.0f / (float)NTOK) + br[e];
      if (sc > best) { best = sc; bi = e; }  // first-max wins (argmax tie-break)
    }
    top1[b] = bi;
    used[bi] = 1;
  }
}

// ---------------------------------------------------------------------------
// Per-expert transpose + fp32->bf16: dst[c][r] = bf16(src[r][c]).
__global__ void wcvt_kernel(const float* __restrict__ src, u16* __restrict__ dst,
                            const int* __restrict__ used, int R, int C) {
  const int e = blockIdx.z;
  if (!used[e]) return;
  __shared__ float tile[64][65];
  const float* s = src + (size_t)e * R * C;
  u16* d = dst + (size_t)e * R * C;
  const int r0 = blockIdx.y * 64, c0 = blockIdx.x * 64;
  const int t = threadIdx.x;
#pragma unroll
  for (int i = 0; i < 16; ++i) {
    int idx = i * 256 + t;
    int r = idx >> 6, c = idx & 63;
    tile[r][c] = s[(size_t)(r0 + r) * C + (c0 + c)];
  }
  __syncthreads();
#pragma unroll
  for (int i = 0; i < 16; ++i) {
    int idx = i * 256 + t;
    int r = idx >> 6, c = idx & 63;
    d[(size_t)(c0 + r) * R + (r0 + c)] = f2bf(tile[c][r]);
  }
}

// ---------------------------------------------------------------------------
// bf16 GEMM, B^T form: C[m][n] = sum_k A[m][k]*Bt[n][k].
// 256x256 block tile, BK=64, 512 threads = 8 waves in 2(M)x4(N); per-wave
// output 128x64 = 8x4 frags of 16x16x32 MFMA. LDS: double-buffered
// (A[256][64] + B[256][64]) bf16 = 2 x 64 KB = 128 KB -> 1 block/CU, 8 waves.
// Rows are 128 B with XOR-8 chunk swizzle (16B chunk c of row r at c^(r&7)),
// applied on the GLOBAL side of global_load_lds; ds_read_b128 fragment reads
// are conflict-free (measured 0 SQ_LDS_BANK_CONFLICT on this scheme).
// Pipeline (T3/T4 minimum-2-phase): prologue stages tiles 0,1; per K-tile:
//   s_waitcnt vmcnt(8)   <- tile t landed, tile t+1 (8 loads) still in flight
//   s_barrier
//   ds_read frags + MFMA (s_setprio 1 around each 32-MFMA cluster)  [T5]
//   s_waitcnt lgkmcnt(0); s_barrier
//   stage tile t+2 into the buffer just freed
// Raw s_barrier (NOT __syncthreads) so the compiler never drains vmcnt(0) in
// the main loop. Exactly 8 VMEM ops per stage keeps the vmcnt arithmetic exact
// (no other VMEM ops inside the loop; spills would break this -> bounds 512,2).
template <bool RELU_BF16>
__global__ void __launch_bounds__(512, 2)
gemm_bt(const u16* __restrict__ Abase, const u16* __restrict__ Btbase,
        const float* __restrict__ biasbase, const int* __restrict__ top1,
        void* __restrict__ OutBase, int K, int Nn, int gx) {
  __shared__ __align__(16) u16 smem[2 * 512 * 64];  // 128 KB: [buf][A 256|B 256][64]

  // T1: XCD-bijective swizzle of linear block id (nwg % 8 == 0 for both GEMMs):
  // consecutive ORIGINAL ids (which share A-panels / B-panels) land on one XCD.
  const int nwg = (int)gridDim.x;
  const int id = (int)blockIdx.x;
  const int swz = (id & 7) * (nwg >> 3) + (id >> 3);
  const int tn = swz % gx;
  const int rem = swz / gx;
  const int tm = rem & 3;   // NTOK/256 == 4
  const int b = rem >> 2;

  const int e = top1[b];
  const u16* A = Abase + (size_t)b * NTOK * K;
  const u16* Bt = Btbase + (size_t)e * Nn * K;
  const float* bias = biasbase + (size_t)e * Nn;

  const int tid = threadIdx.x;
  const int lane = tid & 63, wave = tid >> 6;  // 8 waves
  const int wm = wave >> 2, wn = wave & 3;     // 2 x 4 wave grid

  // staging lane map: lane l -> row l>>3 of an 8-row group; global 16B chunk
  // (l&7)^(row&7) so linear LDS position (l&7) receives swizzled data.
  const int lrow = lane >> 3;
  const int lch = (lane & 7) ^ (lrow & 7);
  const size_t laneOff = (size_t)lrow * K * 2 + (size_t)lch * 16;  // bytes
  const char* gA = (const char*)(A + (size_t)(tm * 256 + wave * 8) * K) + laneOff;
  const char* gB = (const char*)(Bt + (size_t)(tn * 256 + wave * 8) * K) + laneOff;
  const int lbase = wave * 8 * 64;  // u16: wave's 8-row group

  // fragment lane map (16x16x32): m/n = lane&15, k-chunk = lane>>4
  const int fr = lane & 15, fq = lane >> 4;
  const int s7 = fr & 7;
  const int choff0 = ((0 + fq) ^ s7) * 8;  // k-half 0, swizzled, u16 units
  const int choff1 = ((4 + fq) ^ s7) * 8;  // k-half 1
  const int rAoff = (wm * 128 + fr) * 64;
  const int rBoff = (wn * 64 + fr) * 64;

  f32x4 acc[8][4];
#pragma unroll
  for (int i = 0; i < 8; ++i)
#pragma unroll
    for (int j = 0; j < 4; ++j) acc[i][j] = (f32x4)(0.f);

  const int KT = K >> 6;

  // Stage K-tile kt into buffer buf: exactly 8 global_load_lds per thread.
  auto STAGE = [&](int kt, int buf) {
    const size_t kOff = (size_t)kt * 128;  // 64 k-elems = 128 B
    u16* lA = smem + buf * 32768 + lbase;
    u16* lB = smem + buf * 32768 + 16384 + lbase;
    gld16(gA + kOff, lA);
    gld16(gA + (size_t)64 * K * 2 + kOff, lA + 4096);
    gld16(gA + (size_t)128 * K * 2 + kOff, lA + 8192);
    gld16(gA + (size_t)192 * K * 2 + kOff, lA + 12288);
    gld16(gB + kOff, lB);
    gld16(gB + (size_t)64 * K * 2 + kOff, lB + 4096);
    gld16(gB + (size_t)128 * K * 2 + kOff, lB + 8192);
    gld16(gB + (size_t)192 * K * 2 + kOff, lB + 12288);
  };

  STAGE(0, 0);
  if (KT > 1) STAGE(1, 1);

  int cur = 0;
  for (int t = 0; t < KT; ++t) {
    // Wait for tile t's 8 loads; leave tile t+1's 8 in flight (uniform branch).
    if (t + 1 < KT) asm volatile("s_waitcnt vmcnt(8)" ::: "memory");
    else            asm volatile("s_waitcnt vmcnt(0)" ::: "memory");
    __builtin_amdgcn_s_barrier();
    asm volatile("" ::: "memory");

    const u16* bA = smem + cur * 32768 + rAoff;
    const u16* bB = smem + cur * 32768 + 16384 + rBoff;
#pragma unroll
    for (int kh = 0; kh < 2; ++kh) {
      const int c = kh ? choff1 : choff0;
      short8 af[8], bfr[4];
#pragma unroll
      for (int mt = 0; mt < 8; ++mt) af[mt] = *(const short8*)(bA + mt * 1024 + c);
#pragma unroll
      for (int nt = 0; nt < 4; ++nt) bfr[nt] = *(const short8*)(bB + nt * 1024 + c);
      __builtin_amdgcn_s_setprio(1);
#pragma unroll
      for (int mt = 0; mt < 8; ++mt)
#pragma unroll
        for (int nt = 0; nt < 4; ++nt)
          acc[mt][nt] = __builtin_amdgcn_mfma_f32_16x16x32_bf16(af[mt], bfr[nt],
                                                                acc[mt][nt], 0, 0, 0);
      __builtin_amdgcn_s_setprio(0);
    }

    // All this wave's ds_reads complete before anyone overwrites buf[cur].
    asm volatile("s_waitcnt lgkmcnt(0)" ::: "memory");
    __builtin_amdgcn_s_barrier();
    asm volatile("" ::: "memory");
    if (t + 2 < KT) STAGE(t + 2, cur);
    cur ^= 1;
  }

  // epilogue: C/D layout col=lane&15, row=4*(lane>>4)+reg
  const int row0 = tm * 256 + wm * 128 + fq * 4;
  const int col0 = tn * 256 + wn * 64 + fr;
  if constexpr (RELU_BF16) {
    u16* Out = (u16*)OutBase + (size_t)b * NTOK * Nn;
#pragma unroll
    for (int mt = 0; mt < 8; ++mt)
#pragma unroll
      for (int nt = 0; nt < 4; ++nt) {
        const int col = col0 + nt * 16;
        const float bv = bias[col];
        const int rowb = row0 + mt * 16;
#pragma unroll
        for (int r = 0; r < 4; ++r) {
          float v = acc[mt][nt][r] + bv;
          v = fmaxf(v, 0.0f);
          Out[(size_t)(rowb + r) * Nn + col] = f2bf(v);
        }
      }
  } else {
    float* Out = (float*)OutBase + (size_t)b * NTOK * Nn;
#pragma unroll
    for (int mt = 0; mt < 8; ++mt)
#pragma unroll
      for (int nt = 0; nt < 4; ++nt) {
        const int col = col0 + nt * 16;
        const float bv = bias[col];
        const int rowb = row0 + mt * 16;
#pragma unroll
        for (int r = 0; r < 4; ++r)
          Out[(size_t)(rowb + r) * Nn + col] = acc[mt][nt][r] + bv;
      }
  }
}

// ---------------------------------------------------------------------------
extern "C" void kernel_launch(void* const* d_in, const int* in_sizes, int n_in,
                              void* d_out, int out_size, void* d_ws, size_t ws_size,
                              hipStream_t stream) {
  const float* x  = (const float*)d_in[0];
  const float* Wr = (const float*)d_in[1];
  const float* br = (const float*)d_in[2];
  const float* W1 = (const float*)d_in[3];
  const float* b1 = (const float*)d_in[4];
  const float* W2 = (const float*)d_in[5];
  const float* b2 = (const float*)d_in[6];
  float* out = (float*)d_out;
  char* ws = (char*)d_ws;

  // workspace layout (~304 MB):
  int*   top1 = (int*)(ws + 0);              // 64 B
  int*   used = (int*)(ws + 64);             // 32 B   (zeroed by memset below)
  float* sums = (float*)(ws + 4096);         // 64 KB
  u16* xbf = (u16*)(ws + (1ull << 20));      // 32 MB  [B][N][H] bf16
  u16* w1t = (u16*)(ws + (48ull << 20));     // 64 MB  [E][F][H] bf16 (W1^T)
  u16* w2t = (u16*)(ws + (112ull << 20));    // 64 MB  [E][H][F] bf16 (W2^T)
  u16* hbf = (u16*)(ws + (176ull << 20));    // 128 MB [B][N][F] bf16

  hipMemsetAsync((void*)ws, 0, 4096 + D_MODEL * NB * sizeof(float), stream);

  xcvt_kernel<<<dim3(NTOK / 16, NB), 256, 0, stream>>>(x, xbf, sums);
  router_kernel<<<NB, 256, 0, stream>>>(sums, Wr, br, top1, used);
  // W1 [E][H=1024][F=4096] -> [E][F][H]
  wcvt_kernel<<<dim3(D_FF / 64, D_MODEL / 64, NEXP), 256, 0, stream>>>(
      W1, w1t, used, D_MODEL, D_FF);
  // W2 [E][F=4096][H=1024] -> [E][H][F]
  wcvt_kernel<<<dim3(D_MODEL / 64, D_FF / 64, NEXP), 256, 0, stream>>>(
      W2, w2t, used, D_FF, D_MODEL);
  // GEMM1: h = relu(x @ W1 + b1), M=1024, N=4096, K=1024, bf16 out
  gemm_bt<true><<<dim3((D_FF / 256) * 4 * NB), dim3(512), 0, stream>>>(
      xbf, w1t, b1, top1, (void*)hbf, D_MODEL, D_FF, D_FF / 256);
  // GEMM2: out = h @ W2 + b2, M=1024, N=1024, K=4096, fp32 out
  gemm_bt<false><<<dim3((D_MODEL / 256) * 4 * NB), dim3(512), 0, stream>>>(
      hbf, w2t, b2, top1, (void*)out, D_FF, D_MODEL, D_MODEL / 256);
}

// Round 2
// 611.734 us; speedup vs baseline: 1.0578x; 1.0049x over previous
//
#include <hip/hip_runtime.h>

typedef unsigned short u16;
typedef __attribute__((ext_vector_type(4))) unsigned short u16x4;
typedef __attribute__((ext_vector_type(8))) short short8;
typedef __attribute__((ext_vector_type(4))) float f32x4;

#define D_MODEL 1024
#define D_FF    4096
#define NB      16
#define NTOK    1024
#define NEXP    8

#define BARRIER() do { __builtin_amdgcn_s_barrier(); asm volatile("" ::: "memory"); } while (0)

// round-to-nearest-even fp32 -> bf16
__device__ __forceinline__ u16 f2bf(float f) {
  union { float f; unsigned u; } v; v.f = f;
  unsigned r = v.u + 0x7FFFu + ((v.u >> 16) & 1u);
  return (u16)(r >> 16);
}

// async global->LDS, 16B per lane; LDS dest is wave-uniform base + lane*16
__device__ __forceinline__ void gld16(const void* g, void* l) {
  __builtin_amdgcn_global_load_lds(
      (const __attribute__((address_space(1))) unsigned int*)g,
      (__attribute__((address_space(3))) unsigned int*)l,
      16, 0, 0);
}

// ---------------------------------------------------------------------------
// x fp32 -> bf16 + per-(b,h) column sums (for router mean) via atomics.
__global__ void xcvt_kernel(const float* __restrict__ x, u16* __restrict__ xbf,
                            float* __restrict__ sums) {
  const int b = blockIdx.y;
  const int n0 = blockIdx.x * 16;
  const int t = threadIdx.x;
  const int h0 = t * 4;
  const size_t base = ((size_t)b * NTOK + n0) * D_MODEL + h0;
  const float* xp = x + base;
  u16* op = xbf + base;
  float a0 = 0.f, a1 = 0.f, a2 = 0.f, a3 = 0.f;
#pragma unroll
  for (int r = 0; r < 16; ++r) {
    float4 v = *(const float4*)(xp + (size_t)r * D_MODEL);
    a0 += v.x; a1 += v.y; a2 += v.z; a3 += v.w;
    u16x4 o;
    o.x = f2bf(v.x); o.y = f2bf(v.y); o.z = f2bf(v.z); o.w = f2bf(v.w);
    *(u16x4*)(op + (size_t)r * D_MODEL) = o;
  }
  float* s = sums + b * D_MODEL + h0;
  atomicAdd(s + 0, a0); atomicAdd(s + 1, a1);
  atomicAdd(s + 2, a2); atomicAdd(s + 3, a3);
}

// ---------------------------------------------------------------------------
// Router, parallel over batch: block b computes scores[b][:], argmax.
__global__ void router_kernel(const float* __restrict__ sums,
                              const float* __restrict__ Wr,
                              const float* __restrict__ br,
                              int* __restrict__ top1, int* __restrict__ used) {
  __shared__ float part[256][NEXP];
  const int b = blockIdx.x;
  const int t = threadIdx.x;
  float acc[NEXP];
#pragma unroll
  for (int e = 0; e < NEXP; ++e) acc[e] = 0.f;
  const float* s = sums + b * D_MODEL;
  for (int h = t; h < D_MODEL; h += 256) {
    const float sv = s[h];
#pragma unroll
    for (int e = 0; e < NEXP; ++e) acc[e] += sv * Wr[h * NEXP + e];
  }
#pragma unroll
  for (int e = 0; e < NEXP; ++e) part[t][e] = acc[e];
  __syncthreads();
  if (t == 0) {
    float best = -1e30f; int bi = 0;
#pragma unroll
    for (int e = 0; e < NEXP; ++e) {
      float sc = 0.f;
      for (int i = 0; i < 256; ++i) sc += part[i][e];
      sc = sc * (1.0f / (float)NTOK) + br[e];
      if (sc > best) { best = sc; bi = e; }  // first-max wins (argmax tie-break)
    }
    top1[b] = bi;
    used[bi] = 1;
  }
}

// ---------------------------------------------------------------------------
// Per-expert transpose + fp32->bf16: dst[c][r] = bf16(src[r][c]).
__global__ void wcvt_kernel(const float* __restrict__ src, u16* __restrict__ dst,
                            const int* __restrict__ used, int R, int C) {
  const int e = blockIdx.z;
  if (!used[e]) return;
  __shared__ float tile[64][65];
  const float* s = src + (size_t)e * R * C;
  u16* d = dst + (size_t)e * R * C;
  const int r0 = blockIdx.y * 64, c0 = blockIdx.x * 64;
  const int t = threadIdx.x;
#pragma unroll
  for (int i = 0; i < 16; ++i) {
    int idx = i * 256 + t;
    int r = idx >> 6, c = idx & 63;
    tile[r][c] = s[(size_t)(r0 + r) * C + (c0 + c)];
  }
  __syncthreads();
#pragma unroll
  for (int i = 0; i < 16; ++i) {
    int idx = i * 256 + t;
    int r = idx >> 6, c = idx & 63;
    d[(size_t)(c0 + r) * R + (r0 + c)] = f2bf(tile[c][r]);
  }
}

// ---------------------------------------------------------------------------
// bf16 GEMM, B^T form: C[m][n] = sum_k A[m][k]*Bt[n][k].
// 256x256 tile, BK=64, 512 thr = 8 waves (2M x 4N), per-wave out 128x64.
// m201-style 8-phase schedule (4 phases per K-tile, 2 K-tiles per dbuf pair):
// LDS = 2 dbuf x {A_kh0, A_kh1, B_kh0, B_kh1} x 16 KB = 128 KB. Each kh
// region: 256 rows x 64 B (32 k-elems). Slot swizzle within a row's 4 x 16B
// chunks: slot = chunk ^ (r&3) ^ ((r>>2)&3)  (Latin square -> uniform bank
// spread for ds_read_b128 frags; staging applies the inverse permutation on
// the GLOBAL side of global_load_lds, LDS side stays linear).
// Phase p of tile t:  {ds_read frags (4-8 x b128) ; stage 2 x gld16} ->
//   BAR -> lgkmcnt(0) -> setprio(1) 16 MFMA setprio(0) -> [vmcnt] -> BAR.
// Stage schedule: ph0/ph1 stage kh1 of t+1 (dead since t-1 ph3); ph2/ph3
// stage kh0 of t+2 (region freed at t ph1's closing barrier). vmcnt(8) at
// ph1/ph3 ends (8 newer loads always in flight; never drains to 0 mid-loop);
// tail: t==KT-2 -> ph3 vmcnt(4); t==KT-1 -> ph1 vmcnt(0), no stages.
// Exactly 2 gld16 per stage slot keeps the per-wave vmcnt ledger exact.
template <bool RELU_BF16>
__global__ void __launch_bounds__(512, 2)
gemm_bt(const u16* __restrict__ Abase, const u16* __restrict__ Btbase,
        const float* __restrict__ biasbase, const int* __restrict__ top1,
        void* __restrict__ OutBase, int K, int Nn, int gx) {
  __shared__ __align__(16) char smem[131072];

  // T1: XCD-bijective swizzle (nwg % 8 == 0 for both GEMMs).
  const int nwg = (int)gridDim.x;
  const int id = (int)blockIdx.x;
  const int swz = (id & 7) * (nwg >> 3) + (id >> 3);
  const int tn = swz % gx;
  const int rem = swz / gx;
  const int tm = rem & 3;   // NTOK/256 == 4
  const int b = rem >> 2;

  const int e = top1[b];
  const u16* A = Abase + (size_t)b * NTOK * K;
  const u16* Bt = Btbase + (size_t)e * Nn * K;
  const float* bias = biasbase + (size_t)e * Nn;

  const int tid = threadIdx.x;
  const int lane = tid & 63, wave = tid >> 6;  // 8 waves
  const int wm = wave >> 2, wn = wave & 3;     // 2 x 4 wave grid

  // staging map: lane l -> row (l>>2) of a 16-row group, slot l&3; the global
  // chunk fetched into slot s of row r is c = s ^ (r&3) ^ ((r>>2)&3); with
  // 16-row-aligned bases this is the per-lane constant below.
  const int cch = (lane & 3) ^ ((lane >> 2) & 3) ^ ((lane >> 4) & 3);
  const int r0g = wave * 16 + (lane >> 2);        // rows 0..127   (j=0)
  const int r1g = r0g + 128;                      // rows 128..255 (j=1)
  const char* gA0 = (const char*)A + ((size_t)(tm * 256 + r0g) * K) * 2 + cch * 16;
  const char* gA1 = (const char*)A + ((size_t)(tm * 256 + r1g) * K) * 2 + cch * 16;
  const char* gB0 = (const char*)Bt + ((size_t)(tn * 256 + r0g) * K) * 2 + cch * 16;
  const char* gB1 = (const char*)Bt + ((size_t)(tn * 256 + r1g) * K) * 2 + cch * 16;
  char* lds = (char*)smem;
  const int ldsW = wave * 1024;   // j=0 dest offset inside a 16 KB region

  // fragment map (16x16x32): m/n = lane&15, k-chunk = lane>>4
  const int fr = lane & 15, fq = lane >> 4;
  const int slot = fq ^ (fr & 3) ^ ((fr >> 2) & 3);
  const int aOff = (wm * 128 + fr) * 64 + slot * 16;            // within A kh-region
  const int bOff = 32768 + (wn * 64 + fr) * 64 + slot * 16;     // within buf (B kh0)

  f32x4 acc[8][4];
#pragma unroll
  for (int i = 0; i < 8; ++i)
#pragma unroll
    for (int j = 0; j < 4; ++j) acc[i][j] = (f32x4)(0.f);

  const int KT = K >> 6;

  // Stage A (resp. B) kh-half of tile kt into buf[kt&1]: exactly 2 gld16.
  auto SA = [&](int kt, int kh) {
    const size_t g = (size_t)kt * 128 + kh * 64;
    char* d = lds + ((kt & 1) << 16) + (kh << 14) + ldsW;
    gld16(gA0 + g, d);
    gld16(gA1 + g, d + 8192);
  };
  auto SB = [&](int kt, int kh) {
    const size_t g = (size_t)kt * 128 + kh * 64;
    char* d = lds + ((kt & 1) << 16) + 32768 + (kh << 14) + ldsW;
    gld16(gB0 + g, d);
    gld16(gB1 + g, d + 8192);
  };

  // Prologue: T0 kh0 (4), T0 kh1 (4), T1 kh0 (4); oldest 4 = T0 kh0.
  SA(0, 0); SB(0, 0);
  SA(0, 1); SB(0, 1);
  SA(1, 0); SB(1, 0);
  asm volatile("s_waitcnt vmcnt(8)" ::: "memory");
  BARRIER();

  for (int t = 0; t < KT; ++t) {
    const char* bb = lds + ((t & 1) << 16);
    const char* pA = bb + aOff;
    const char* pB = bb + bOff;
    short8 af[4], bfr[4];

    // ---- ph0: kh0, mt 0-3 (reads B kh0 once, kept for ph1) ----
#pragma unroll
    for (int nt = 0; nt < 4; ++nt) bfr[nt] = *(const short8*)(pB + nt * 1024);
#pragma unroll
    for (int mt = 0; mt < 4; ++mt) af[mt] = *(const short8*)(pA + mt * 1024);
    if (t + 1 < KT) SA(t + 1, 1);
    BARRIER();
    asm volatile("s_waitcnt lgkmcnt(0)" ::: "memory");
    __builtin_amdgcn_s_setprio(1);
#pragma unroll
    for (int mt = 0; mt < 4; ++mt)
#pragma unroll
      for (int nt = 0; nt < 4; ++nt)
        acc[mt][nt] = __builtin_amdgcn_mfma_f32_16x16x32_bf16(af[mt], bfr[nt],
                                                              acc[mt][nt], 0, 0, 0);
    __builtin_amdgcn_s_setprio(0);
    BARRIER();

    // ---- ph1: kh0, mt 4-7 ----
#pragma unroll
    for (int mt = 0; mt < 4; ++mt) af[mt] = *(const short8*)(pA + (mt + 4) * 1024);
    if (t + 1 < KT) SB(t + 1, 1);
    BARRIER();
    asm volatile("s_waitcnt lgkmcnt(0)" ::: "memory");
    __builtin_amdgcn_s_setprio(1);
#pragma unroll
    for (int mt = 0; mt < 4; ++mt)
#pragma unroll
      for (int nt = 0; nt < 4; ++nt)
        acc[mt + 4][nt] = __builtin_amdgcn_mfma_f32_16x16x32_bf16(af[mt], bfr[nt],
                                                                  acc[mt + 4][nt], 0, 0, 0);
    __builtin_amdgcn_s_setprio(0);
    // ensure T kh1 landed before ph2's ds_reads (8 newer loads in flight)
    if (t == KT - 1) asm volatile("s_waitcnt vmcnt(0)" ::: "memory");
    else             asm volatile("s_waitcnt vmcnt(8)" ::: "memory");
    BARRIER();

    // ---- ph2: kh1, mt 0-3 ----
#pragma unroll
    for (int nt = 0; nt < 4; ++nt) bfr[nt] = *(const short8*)(pB + 16384 + nt * 1024);
#pragma unroll
    for (int mt = 0; mt < 4; ++mt) af[mt] = *(const short8*)(pA + 16384 + mt * 1024);
    if (t + 2 < KT) SA(t + 2, 0);
    BARRIER();
    asm volatile("s_waitcnt lgkmcnt(0)" ::: "memory");
    __builtin_amdgcn_s_setprio(1);
#pragma unroll
    for (int mt = 0; mt < 4; ++mt)
#pragma unroll
      for (int nt = 0; nt < 4; ++nt)
        acc[mt][nt] = __builtin_amdgcn_mfma_f32_16x16x32_bf16(af[mt], bfr[nt],
                                                              acc[mt][nt], 0, 0, 0);
    __builtin_amdgcn_s_setprio(0);
    BARRIER();

    // ---- ph3: kh1, mt 4-7 ----
#pragma unroll
    for (int mt = 0; mt < 4; ++mt) af[mt] = *(const short8*)(pA + 16384 + (mt + 4) * 1024);
    if (t + 2 < KT) SB(t + 2, 0);
    BARRIER();
    asm volatile("s_waitcnt lgkmcnt(0)" ::: "memory");
    __builtin_amdgcn_s_setprio(1);
#pragma unroll
    for (int mt = 0; mt < 4; ++mt)
#pragma unroll
      for (int nt = 0; nt < 4; ++nt)
        acc[mt + 4][nt] = __builtin_amdgcn_mfma_f32_16x16x32_bf16(af[mt], bfr[nt],
                                                                  acc[mt + 4][nt], 0, 0, 0);
    __builtin_amdgcn_s_setprio(0);
    // ensure T+1 kh0 landed before next tile's ph0 ds_reads
    if (t < KT - 2)       asm volatile("s_waitcnt vmcnt(8)" ::: "memory");
    else if (t == KT - 2) asm volatile("s_waitcnt vmcnt(4)" ::: "memory");
    BARRIER();
  }

  // epilogue: C/D layout col=lane&15, row=4*(lane>>4)+reg
  const int row0 = tm * 256 + wm * 128 + fq * 4;
  const int col0 = tn * 256 + wn * 64 + fr;
  if constexpr (RELU_BF16) {
    u16* Out = (u16*)OutBase + (size_t)b * NTOK * Nn;
#pragma unroll
    for (int mt = 0; mt < 8; ++mt)
#pragma unroll
      for (int nt = 0; nt < 4; ++nt) {
        const int col = col0 + nt * 16;
        const float bv = bias[col];
        const int rowb = row0 + mt * 16;
#pragma unroll
        for (int r = 0; r < 4; ++r) {
          float v = acc[mt][nt][r] + bv;
          v = fmaxf(v, 0.0f);
          Out[(size_t)(rowb + r) * Nn + col] = f2bf(v);
        }
      }
  } else {
    float* Out = (float*)OutBase + (size_t)b * NTOK * Nn;
#pragma unroll
    for (int mt = 0; mt < 8; ++mt)
#pragma unroll
      for (int nt = 0; nt < 4; ++nt) {
        const int col = col0 + nt * 16;
        const float bv = bias[col];
        const int rowb = row0 + mt * 16;
#pragma unroll
        for (int r = 0; r < 4; ++r)
          Out[(size_t)(rowb + r) * Nn + col] = acc[mt][nt][r] + bv;
      }
  }
}

// ---------------------------------------------------------------------------
extern "C" void kernel_launch(void* const* d_in, const int* in_sizes, int n_in,
                              void* d_out, int out_size, void* d_ws, size_t ws_size,
                              hipStream_t stream) {
  const float* x  = (const float*)d_in[0];
  const float* Wr = (const float*)d_in[1];
  const float* br = (const float*)d_in[2];
  const float* W1 = (const float*)d_in[3];
  const float* b1 = (const float*)d_in[4];
  const float* W2 = (const float*)d_in[5];
  const float* b2 = (const float*)d_in[6];
  float* out = (float*)d_out;
  char* ws = (char*)d_ws;

  // workspace layout (~304 MB):
  int*   top1 = (int*)(ws + 0);              // 64 B
  int*   used = (int*)(ws + 64);             // 32 B   (zeroed by memset below)
  float* sums = (float*)(ws + 4096);         // 64 KB
  u16* xbf = (u16*)(ws + (1ull << 20));      // 32 MB  [B][N][H] bf16
  u16* w1t = (u16*)(ws + (48ull << 20));     // 64 MB  [E][F][H] bf16 (W1^T)
  u16* w2t = (u16*)(ws + (112ull << 20));    // 64 MB  [E][H][F] bf16 (W2^T)
  u16* hbf = (u16*)(ws + (176ull << 20));    // 128 MB [B][N][F] bf16

  hipMemsetAsync((void*)ws, 0, 4096 + D_MODEL * NB * sizeof(float), stream);

  xcvt_kernel<<<dim3(NTOK / 16, NB), 256, 0, stream>>>(x, xbf, sums);
  router_kernel<<<NB, 256, 0, stream>>>(sums, Wr, br, top1, used);
  // W1 [E][H=1024][F=4096] -> [E][F][H]
  wcvt_kernel<<<dim3(D_FF / 64, D_MODEL / 64, NEXP), 256, 0, stream>>>(
      W1, w1t, used, D_MODEL, D_FF);
  // W2 [E][F=4096][H=1024] -> [E][H][F]
  wcvt_kernel<<<dim3(D_MODEL / 64, D_FF / 64, NEXP), 256, 0, stream>>>(
      W2, w2t, used, D_FF, D_MODEL);
  // GEMM1: h = relu(x @ W1 + b1), M=1024, N=4096, K=1024, bf16 out
  gemm_bt<true><<<dim3((D_FF / 256) * 4 * NB), dim3(512), 0, stream>>>(
      xbf, w1t, b1, top1, (void*)hbf, D_MODEL, D_FF, D_FF / 256);
  // GEMM2: out = h @ W2 + b2, M=1024, N=1024, K=4096, fp32 out
  gemm_bt<false><<<dim3((D_MODEL / 256) * 4 * NB), dim3(512), 0, stream>>>(
      hbf, w2t, b2, top1, (void*)out, D_FF, D_MODEL, D_MODEL / 256);
}

// Round 3
// 604.284 us; speedup vs baseline: 1.0708x; 1.0123x over previous
//
#include <hip/hip_runtime.h>

typedef unsigned short u16;
typedef __attribute__((ext_vector_type(4))) unsigned short u16x4;
typedef __attribute__((ext_vector_type(8))) short short8;
typedef __attribute__((ext_vector_type(4))) float f32x4;

#define D_MODEL 1024
#define D_FF    4096
#define NB      16
#define NTOK    1024
#define NEXP    8

#define BARRIER() do { __builtin_amdgcn_s_barrier(); asm volatile("" ::: "memory"); } while (0)

// round-to-nearest-even fp32 -> bf16
__device__ __forceinline__ u16 f2bf(float f) {
  union { float f; unsigned u; } v; v.f = f;
  unsigned r = v.u + 0x7FFFu + ((v.u >> 16) & 1u);
  return (u16)(r >> 16);
}

// async global->LDS, 16B per lane; LDS dest is wave-uniform base + lane*16
__device__ __forceinline__ void gld16(const void* g, void* l) {
  __builtin_amdgcn_global_load_lds(
      (const __attribute__((address_space(1))) unsigned int*)g,
      (__attribute__((address_space(3))) unsigned int*)l,
      16, 0, 0);
}

// ---------------------------------------------------------------------------
// x fp32 -> bf16 + per-(b,h) column sums (for router mean) via atomics.
__global__ void xcvt_kernel(const float* __restrict__ x, u16* __restrict__ xbf,
                            float* __restrict__ sums) {
  const int b = blockIdx.y;
  const int n0 = blockIdx.x * 16;
  const int t = threadIdx.x;
  const int h0 = t * 4;
  const size_t base = ((size_t)b * NTOK + n0) * D_MODEL + h0;
  const float* xp = x + base;
  u16* op = xbf + base;
  float a0 = 0.f, a1 = 0.f, a2 = 0.f, a3 = 0.f;
#pragma unroll
  for (int r = 0; r < 16; ++r) {
    float4 v = *(const float4*)(xp + (size_t)r * D_MODEL);
    a0 += v.x; a1 += v.y; a2 += v.z; a3 += v.w;
    u16x4 o;
    o.x = f2bf(v.x); o.y = f2bf(v.y); o.z = f2bf(v.z); o.w = f2bf(v.w);
    *(u16x4*)(op + (size_t)r * D_MODEL) = o;
  }
  float* s = sums + b * D_MODEL + h0;
  atomicAdd(s + 0, a0); atomicAdd(s + 1, a1);
  atomicAdd(s + 2, a2); atomicAdd(s + 3, a3);
}

// ---------------------------------------------------------------------------
// Router, parallel over batch: block b computes scores[b][:], argmax.
__global__ void router_kernel(const float* __restrict__ sums,
                              const float* __restrict__ Wr,
                              const float* __restrict__ br,
                              int* __restrict__ top1, int* __restrict__ used) {
  __shared__ float part[256][NEXP];
  const int b = blockIdx.x;
  const int t = threadIdx.x;
  float acc[NEXP];
#pragma unroll
  for (int e = 0; e < NEXP; ++e) acc[e] = 0.f;
  const float* s = sums + b * D_MODEL;
  for (int h = t; h < D_MODEL; h += 256) {
    const float sv = s[h];
#pragma unroll
    for (int e = 0; e < NEXP; ++e) acc[e] += sv * Wr[h * NEXP + e];
  }
#pragma unroll
  for (int e = 0; e < NEXP; ++e) part[t][e] = acc[e];
  __syncthreads();
  if (t == 0) {
    float best = -1e30f; int bi = 0;
#pragma unroll
    for (int e = 0; e < NEXP; ++e) {
      float sc = 0.f;
      for (int i = 0; i < 256; ++i) sc += part[i][e];
      sc = sc * (1.0f / (float)NTOK) + br[e];
      if (sc > best) { best = sc; bi = e; }  // first-max wins (argmax tie-break)
    }
    top1[b] = bi;
    used[bi] = 1;
  }
}

// ---------------------------------------------------------------------------
// Per-expert transpose + fp32->bf16: dst[c][r] = bf16(src[r][c]).
__global__ void wcvt_kernel(const float* __restrict__ src, u16* __restrict__ dst,
                            const int* __restrict__ used, int R, int C) {
  const int e = blockIdx.z;
  if (!used[e]) return;
  __shared__ float tile[64][65];
  const float* s = src + (size_t)e * R * C;
  u16* d = dst + (size_t)e * R * C;
  const int r0 = blockIdx.y * 64, c0 = blockIdx.x * 64;
  const int t = threadIdx.x;
#pragma unroll
  for (int i = 0; i < 16; ++i) {
    int idx = i * 256 + t;
    int r = idx >> 6, c = idx & 63;
    tile[r][c] = s[(size_t)(r0 + r) * C + (c0 + c)];
  }
  __syncthreads();
#pragma unroll
  for (int i = 0; i < 16; ++i) {
    int idx = i * 256 + t;
    int r = idx >> 6, c = idx & 63;
    d[(size_t)(c0 + r) * R + (r0 + c)] = f2bf(tile[c][r]);
  }
}

// ---------------------------------------------------------------------------
// bf16 GEMM, B^T form: C[m][n] = sum_k A[m][k]*Bt[n][k].
// 256x256 tile, BK=64, 512 thr = 8 waves (2M x 4N), per-wave out 128x64.
// LDS layout: BYTE-IDENTICAL to the measured-0-conflict round-1 kernel:
// 2 dbuf x (A 256 rows + B 256 rows) x 128 B. 16B chunk c of row r stored at
// position c^(r&7) (swizzle applied on the GLOBAL side of global_load_lds;
// LDS dest stays wave-uniform + lane*16). Fragment ds_read_b128 at chunk
// ((kh*4+fq)^(fr&7)) -> measured SQ_LDS_BANK_CONFLICT == 0.
// Schedule: 4 phases per K-tile (T3/T4), stages placed by ROW-death:
//   ph0: read kh0 frags mt0-3 (+B) ; stage A-ops{1,3} of t+1 (rows 64-127/
//        192-255 of buf^1, dead since t-1 ph3) ; MFMA ; vmcnt(8)
//   ph1: read kh0 frags mt4-7 ; MFMA
//   ph2: read kh1 frags mt0-3 (+B) ; MFMA        <- last read of A-lo + all B
//   ph3: read kh1 frags mt4-7 ; stage A-ops{0,2}+B-ops{0-3} of t+2 into buf
//        cur (those rows dead at ph2's closing barrier) ; MFMA ; vmcnt(8)
// Per-wave vmcnt ledger (2 gld16 @ph0, 6 @ph3, in-order completion):
//   ph0-end: need A13(t) [t-1 ph0]; newer = A02B(t+1) 6 + A13(t+1) 2 = 8.
//   ph3-end: need A02B(t+1) [t ... t-1? issued t ph3? no: t-1 ph3]; newer =
//            A13(t+1) 2 + A02B(t+2) 6 = 8.  Tails: vmcnt(0)/vmcnt(2).
// No mid-loop drain; raw s_barrier so the compiler never inserts vmcnt(0).
template <bool RELU_BF16>
__global__ void __launch_bounds__(512, 2)
gemm_bt(const u16* __restrict__ Abase, const u16* __restrict__ Btbase,
        const float* __restrict__ biasbase, const int* __restrict__ top1,
        void* __restrict__ OutBase, int K, int Nn, int gx) {
  __shared__ __align__(16) u16 smem[2 * 512 * 64];  // 128 KB

  // T1: XCD-bijective swizzle (nwg % 8 == 0 for both GEMMs).
  const int nwg = (int)gridDim.x;
  const int id = (int)blockIdx.x;
  const int swz = (id & 7) * (nwg >> 3) + (id >> 3);
  const int tn = swz % gx;
  const int rem = swz / gx;
  const int tm = rem & 3;   // NTOK/256 == 4
  const int b = rem >> 2;

  const int e = top1[b];
  const u16* A = Abase + (size_t)b * NTOK * K;
  const u16* Bt = Btbase + (size_t)e * Nn * K;
  const float* bias = biasbase + (size_t)e * Nn;

  const int tid = threadIdx.x;
  const int lane = tid & 63, wave = tid >> 6;  // 8 waves
  const int wm = wave >> 2, wn = wave & 3;     // 2 x 4 wave grid

  // staging lane map (round-1 verbatim): lane l -> row l>>3 of an 8-row
  // group; global 16B chunk (l&7)^(row&7) so linear LDS position (l&7)
  // receives swizzled data.
  const int lrow = lane >> 3;
  const int lch = (lane & 7) ^ (lrow & 7);
  const size_t laneOff = (size_t)lrow * K * 2 + (size_t)lch * 16;  // bytes
  const char* gA = (const char*)(A + (size_t)(tm * 256 + wave * 8) * K) + laneOff;
  const char* gB = (const char*)(Bt + (size_t)(tn * 256 + wave * 8) * K) + laneOff;
  const int lbase = wave * 8 * 64;  // u16: wave's 8-row group

  // fragment map (16x16x32): m/n = lane&15, k-chunk = lane>>4
  const int fr = lane & 15, fq = lane >> 4;
  const int s7 = fr & 7;
  const int choff0 = ((0 + fq) ^ s7) * 8;  // kh0 chunk, swizzled, u16 units
  const int choff1 = ((4 + fq) ^ s7) * 8;  // kh1 chunk
  const int rAoff = (wm * 128 + fr) * 64;
  const int rBoff = 16384 + (wn * 64 + fr) * 64;

  f32x4 acc[8][4];
#pragma unroll
  for (int i = 0; i < 8; ++i)
#pragma unroll
    for (int j = 0; j < 4; ++j) acc[i][j] = (f32x4)(0.f);

  const int KT = K >> 6;

  // Stage groups for tile kt into buf kt&1 (round-1 addresses, split by row
  // death). A op i covers rows {i*64 + wave*8 .. +7}; B likewise.
  auto S_A02B = [&](int kt) {  // A rows 0-63,128-191 + all B: 6 gld16
    const int buf = kt & 1;
    const size_t kOff = (size_t)kt * 128;
    u16* lA = smem + buf * 32768 + lbase;
    u16* lB = smem + buf * 32768 + 16384 + lbase;
    gld16(gA + kOff, lA);
    gld16(gA + (size_t)128 * K * 2 + kOff, lA + 8192);
    gld16(gB + kOff, lB);
    gld16(gB + (size_t)64 * K * 2 + kOff, lB + 4096);
    gld16(gB + (size_t)128 * K * 2 + kOff, lB + 8192);
    gld16(gB + (size_t)192 * K * 2 + kOff, lB + 12288);
  };
  auto S_A13 = [&](int kt) {   // A rows 64-127,192-255: 2 gld16
    const int buf = kt & 1;
    const size_t kOff = (size_t)kt * 128;
    u16* lA = smem + buf * 32768 + lbase;
    gld16(gA + (size_t)64 * K * 2 + kOff, lA + 4096);
    gld16(gA + (size_t)192 * K * 2 + kOff, lA + 12288);
  };

  // Prologue: A02B(0) 6, A13(0) 2, A02B(1) 6 -> wait oldest 6 landed.
  S_A02B(0);
  S_A13(0);
  if (KT > 1) S_A02B(1);
  asm volatile("s_waitcnt vmcnt(8)" ::: "memory");
  BARRIER();

  for (int t = 0; t < KT; ++t) {
    const u16* pA = smem + (t & 1) * 32768 + rAoff;
    const u16* pB = smem + (t & 1) * 32768 + rBoff;
    short8 af[4], bfr[4];

    // ---- ph0: kh0, mt 0-3 (B kh0 read once, held for ph1) ----
#pragma unroll
    for (int nt = 0; nt < 4; ++nt) bfr[nt] = *(const short8*)(pB + nt * 1024 + choff0);
#pragma unroll
    for (int mt = 0; mt < 4; ++mt) af[mt] = *(const short8*)(pA + mt * 1024 + choff0);
    if (t + 1 < KT) S_A13(t + 1);
    BARRIER();
    asm volatile("s_waitcnt lgkmcnt(0)" ::: "memory");
    __builtin_amdgcn_s_setprio(1);
#pragma unroll
    for (int mt = 0; mt < 4; ++mt)
#pragma unroll
      for (int nt = 0; nt < 4; ++nt)
        acc[mt][nt] = __builtin_amdgcn_mfma_f32_16x16x32_bf16(af[mt], bfr[nt],
                                                              acc[mt][nt], 0, 0, 0);
    __builtin_amdgcn_s_setprio(0);
    // guards ph1's reads of A rows 64-127/192-255 (A13(t), issued t-1 ph0)
    if (t + 1 < KT) asm volatile("s_waitcnt vmcnt(8)" ::: "memory");
    else            asm volatile("s_waitcnt vmcnt(0)" ::: "memory");
    BARRIER();

    // ---- ph1: kh0, mt 4-7 ----
#pragma unroll
    for (int mt = 0; mt < 4; ++mt) af[mt] = *(const short8*)(pA + (mt + 4) * 1024 + choff0);
    BARRIER();
    asm volatile("s_waitcnt lgkmcnt(0)" ::: "memory");
    __builtin_amdgcn_s_setprio(1);
#pragma unroll
    for (int mt = 0; mt < 4; ++mt)
#pragma unroll
      for (int nt = 0; nt < 4; ++nt)
        acc[mt + 4][nt] = __builtin_amdgcn_mfma_f32_16x16x32_bf16(af[mt], bfr[nt],
                                                                  acc[mt + 4][nt], 0, 0, 0);
    __builtin_amdgcn_s_setprio(0);
    BARRIER();

    // ---- ph2: kh1, mt 0-3 (last read of A-lo quarters + ALL B rows) ----
#pragma unroll
    for (int nt = 0; nt < 4; ++nt) bfr[nt] = *(const short8*)(pB + nt * 1024 + choff1);
#pragma unroll
    for (int mt = 0; mt < 4; ++mt) af[mt] = *(const short8*)(pA + mt * 1024 + choff1);
    BARRIER();
    asm volatile("s_waitcnt lgkmcnt(0)" ::: "memory");
    __builtin_amdgcn_s_setprio(1);
#pragma unroll
    for (int mt = 0; mt < 4; ++mt)
#pragma unroll
      for (int nt = 0; nt < 4; ++nt)
        acc[mt][nt] = __builtin_amdgcn_mfma_f32_16x16x32_bf16(af[mt], bfr[nt],
                                                              acc[mt][nt], 0, 0, 0);
    __builtin_amdgcn_s_setprio(0);
    BARRIER();

    // ---- ph3: kh1, mt 4-7; stage t+2 into rows freed at ph2's barrier ----
#pragma unroll
    for (int mt = 0; mt < 4; ++mt) af[mt] = *(const short8*)(pA + (mt + 4) * 1024 + choff1);
    if (t + 2 < KT) S_A02B(t + 2);
    BARRIER();
    asm volatile("s_waitcnt lgkmcnt(0)" ::: "memory");
    __builtin_amdgcn_s_setprio(1);
#pragma unroll
    for (int mt = 0; mt < 4; ++mt)
#pragma unroll
      for (int nt = 0; nt < 4; ++nt)
        acc[mt + 4][nt] = __builtin_amdgcn_mfma_f32_16x16x32_bf16(af[mt], bfr[nt],
                                                                  acc[mt + 4][nt], 0, 0, 0);
    __builtin_amdgcn_s_setprio(0);
    // guards next tile's ph0 (A02B(t+1), issued t-1 ph3)
    if (t + 2 < KT)       asm volatile("s_waitcnt vmcnt(8)" ::: "memory");
    else if (t == KT - 2) asm volatile("s_waitcnt vmcnt(2)" ::: "memory");
    BARRIER();
  }

  // epilogue: C/D layout col=lane&15, row=4*(lane>>4)+reg
  const int row0 = tm * 256 + wm * 128 + fq * 4;
  const int col0 = tn * 256 + wn * 64 + fr;
  if constexpr (RELU_BF16) {
    u16* Out = (u16*)OutBase + (size_t)b * NTOK * Nn;
#pragma unroll
    for (int mt = 0; mt < 8; ++mt)
#pragma unroll
      for (int nt = 0; nt < 4; ++nt) {
        const int col = col0 + nt * 16;
        const float bv = bias[col];
        const int rowb = row0 + mt * 16;
#pragma unroll
        for (int r = 0; r < 4; ++r) {
          float v = acc[mt][nt][r] + bv;
          v = fmaxf(v, 0.0f);
          Out[(size_t)(rowb + r) * Nn + col] = f2bf(v);
        }
      }
  } else {
    float* Out = (float*)OutBase + (size_t)b * NTOK * Nn;
#pragma unroll
    for (int mt = 0; mt < 8; ++mt)
#pragma unroll
      for (int nt = 0; nt < 4; ++nt) {
        const int col = col0 + nt * 16;
        const float bv = bias[col];
        const int rowb = row0 + mt * 16;
#pragma unroll
        for (int r = 0; r < 4; ++r)
          Out[(size_t)(rowb + r) * Nn + col] = acc[mt][nt][r] + bv;
      }
  }
}

// ---------------------------------------------------------------------------
extern "C" void kernel_launch(void* const* d_in, const int* in_sizes, int n_in,
                              void* d_out, int out_size, void* d_ws, size_t ws_size,
                              hipStream_t stream) {
  const float* x  = (const float*)d_in[0];
  const float* Wr = (const float*)d_in[1];
  const float* br = (const float*)d_in[2];
  const float* W1 = (const float*)d_in[3];
  const float* b1 = (const float*)d_in[4];
  const float* W2 = (const float*)d_in[5];
  const float* b2 = (const float*)d_in[6];
  float* out = (float*)d_out;
  char* ws = (char*)d_ws;

  // workspace layout (~304 MB):
  int*   top1 = (int*)(ws + 0);              // 64 B
  int*   used = (int*)(ws + 64);             // 32 B   (zeroed by memset below)
  float* sums = (float*)(ws + 4096);         // 64 KB
  u16* xbf = (u16*)(ws + (1ull << 20));      // 32 MB  [B][N][H] bf16
  u16* w1t = (u16*)(ws + (48ull << 20));     // 64 MB  [E][F][H] bf16 (W1^T)
  u16* w2t = (u16*)(ws + (112ull << 20));    // 64 MB  [E][H][F] bf16 (W2^T)
  u16* hbf = (u16*)(ws + (176ull << 20));    // 128 MB [B][N][F] bf16

  hipMemsetAsync((void*)ws, 0, 4096 + D_MODEL * NB * sizeof(float), stream);

  xcvt_kernel<<<dim3(NTOK / 16, NB), 256, 0, stream>>>(x, xbf, sums);
  router_kernel<<<NB, 256, 0, stream>>>(sums, Wr, br, top1, used);
  // W1 [E][H=1024][F=4096] -> [E][F][H]
  wcvt_kernel<<<dim3(D_FF / 64, D_MODEL / 64, NEXP), 256, 0, stream>>>(
      W1, w1t, used, D_MODEL, D_FF);
  // W2 [E][F=4096][H=1024] -> [E][H][F]
  wcvt_kernel<<<dim3(D_MODEL / 64, D_FF / 64, NEXP), 256, 0, stream>>>(
      W2, w2t, used, D_FF, D_MODEL);
  // GEMM1: h = relu(x @ W1 + b1), M=1024, N=4096, K=1024, bf16 out
  gemm_bt<true><<<dim3((D_FF / 256) * 4 * NB), dim3(512), 0, stream>>>(
      xbf, w1t, b1, top1, (void*)hbf, D_MODEL, D_FF, D_FF / 256);
  // GEMM2: out = h @ W2 + b2, M=1024, N=1024, K=4096, fp32 out
  gemm_bt<false><<<dim3((D_MODEL / 256) * 4 * NB), dim3(512), 0, stream>>>(
      hbf, w2t, b2, top1, (void*)out, D_FF, D_MODEL, D_MODEL / 256);
}